// Round 3
// baseline (287.859 us; speedup 1.0000x reference)
//
#include <hip/hip_runtime.h>

#define NUM_EMBED 1024
#define EMBED_DIM 256
#define SPATIAL 4096          // 64*64
#define NROWS 65536           // 16*4096
#define EMBED_ELEMS 16777216  // 16*256*4096
#define MARGIN 0.1f

typedef _Float16 half8 __attribute__((ext_vector_type(8)));
typedef float f32x4 __attribute__((ext_vector_type(4)));

__device__ __forceinline__ unsigned fkey(float f) {
  unsigned u = __float_as_uint(f);
  return (u & 0x80000000u) ? ~u : (u | 0x80000000u);
}

__device__ __forceinline__ void gll16(const void* g, void* l) {
  __builtin_amdgcn_global_load_lds((const __attribute__((address_space(1))) void*)g,
                                   (__attribute__((address_space(3))) void*)l, 16, 0, 0);
}

// ---------------- init: packed mins, used, flagcount, cnorm, cb16 ----------------
__global__ __launch_bounds__(256) void k_init(const float* __restrict__ cb,
                                              unsigned long long* __restrict__ packed,
                                              int* __restrict__ used,
                                              int* __restrict__ flagcount,
                                              float* __restrict__ cnorm,
                                              _Float16* __restrict__ cb16) {
  int bid = blockIdx.x, tid = threadIdx.x;
  if (bid < 256) {
    packed[bid * 256 + tid] = ~0ull;
  } else if (bid == 256) {
    used[tid] = 0; used[tid + 256] = 0; used[tid + 512] = 0; used[tid + 768] = 0;
    if (tid == 0) *flagcount = 0;
  } else if (bid < 321) {
    int c = (bid - 257) * 16 + (tid >> 4);
    int l = tid & 15;
    const float4* p = (const float4*)(cb + c * EMBED_DIM + l * 16);
    float s = 0.f;
#pragma unroll
    for (int j = 0; j < 4; ++j) {
      float4 v = p[j];
      s += v.x * v.x + v.y * v.y + v.z * v.z + v.w * v.w;
    }
#pragma unroll
    for (int off = 1; off < 16; off <<= 1) s += __shfl_xor(s, off, 16);
    if (l == 0) cnorm[c] = s;
  } else {
    // fp16 codebook: 128 blocks, thread -> 8 halves
    int gid = (bid - 321) * 256 + tid;  // 0..32767
    const float4* src = (const float4*)(cb + gid * 8);
    float4 a = src[0], b = src[1];
    half8 h;
    h[0] = (_Float16)a.x; h[1] = (_Float16)a.y; h[2] = (_Float16)a.z; h[3] = (_Float16)a.w;
    h[4] = (_Float16)b.x; h[5] = (_Float16)b.y; h[6] = (_Float16)b.z; h[7] = (_Float16)b.w;
    *(half8*)(cb16 + gid * 8) = h;
  }
}

// ---------------- fp16 MFMA screening ----------------
// block: 64 rows x 1024 codes (4 chunks of 256). 4 waves; wave = 64 codes x 64 rows.
// Xs: [64 s][256 k] fp16, swizzled. As: double-buffered [256 code][32 k] fp16,
// loaded by global_load_lds with source-side swizzle (LDS linear).
__global__ __launch_bounds__(256, 2) void k_score(const float* __restrict__ in,
                                                  const _Float16* __restrict__ cb16,
                                                  const float* __restrict__ cnorm,
                                                  float* __restrict__ out_idx,
                                                  int* __restrict__ idxi,
                                                  int* __restrict__ flagged,
                                                  int* __restrict__ flagcount) {
  __shared__ _Float16 Xs[16384];     // 32 KB
  __shared__ _Float16 As[2][8192];   // 2 x 16 KB
  int tid = threadIdx.x;
  int lane = tid & 63;
  int wave = tid >> 6;
  int ln = lane & 15;
  int kg = (lane >> 4) << 4;  // byte offset of this lane-group's 8-half k slice
  int r0 = blockIdx.x << 6;
  const float* Ain = in + ((r0 >> 12) * (EMBED_DIM * SPATIAL)) + (r0 & 4095);

  // per-lane global_load_lds source mapping (loop-invariant parts)
  const _Float16* psrc[4];
  int ldst[4];
#pragma unroll
  for (int i = 0; i < 4; ++i) {
    int o = (i * 4 + wave) * 1024 + (lane << 4);  // linear LDS byte offset
    int c = o >> 6;                                // code 0..255 within tile
    int s = (o >> 4) & 3;                          // 16B slot within code
    psrc[i] = cb16 + c * 256 + ((s ^ (c & 3)) << 3);
    ldst[i] = o;
  }

  // issue As[0] stage for step 0 (cc=0, ks=0)
#pragma unroll
  for (int i = 0; i < 4; ++i) gll16(psrc[i], (char*)As[0] + ldst[i]);

  // ---- stage X (fp32 -> fp16, transposed to [s][k], swizzled) ----
  {
    int sl = tid & 63;
    int kgrp = tid >> 6;
    int swz = (sl & 31) << 4;
    const float* p0 = Ain + sl;
#pragma unroll
    for (int j = 0; j < 8; ++j) {
      int k0 = kgrp * 8 + j * 32;
      half8 h;
#pragma unroll
      for (int q = 0; q < 8; ++q) h[q] = (_Float16)p0[(k0 + q) * SPATIAL];
      *(half8*)((char*)Xs + (sl << 9) + ((k0 << 1) ^ swz)) = h;
    }
  }
  __syncthreads();  // X + As[0] visible (syncthreads drains vmcnt+lgkmcnt)

  f32x4 acc[4][4] = {};
  float sv1[4], sv2[4];
  int si1[4];
#pragma unroll
  for (int nf = 0; nf < 4; ++nf) { sv1[nf] = 3e38f; sv2[nf] = 3e38f; si1[nf] = 0; }

  int abyte0 = (wave * 64 + ln) * 64 + (kg ^ ((ln & 3) << 4));

  for (int sc = 0; sc < 32; ++sc) {
    int cc = sc >> 3, ks = sc & 7;
    int cur = sc & 1, nxt = cur ^ 1;
    // issue stage of next step into As[nxt]
    if (sc < 31) {
      int nstep = sc + 1;
      int goff = ((nstep >> 3) << 16) + ((nstep & 7) << 5);
      char* base = (char*)As[nxt];
#pragma unroll
      for (int i = 0; i < 4; ++i) gll16(psrc[i] + goff, base + ldst[i]);
    }
    // fragments + MFMA
    half8 af[4], bf[4];
#pragma unroll
    for (int mf = 0; mf < 4; ++mf)
      af[mf] = *(const half8*)((const char*)As[cur] + abyte0 + mf * 1024);
#pragma unroll
    for (int nf = 0; nf < 4; ++nf) {
      int sl = nf * 16 + ln;
      bf[nf] = *(const half8*)((const char*)Xs + (sl << 9) +
                               (((ks << 6) + kg) ^ ((sl & 31) << 4)));
    }
#pragma unroll
    for (int nf = 0; nf < 4; ++nf)
#pragma unroll
      for (int mf = 0; mf < 4; ++mf)
        acc[mf][nf] = __builtin_amdgcn_mfma_f32_16x16x32_f16(af[mf], bf[nf], acc[mf][nf], 0, 0, 0);
    if (ks == 7) {
      // fold chunk cc into thread-local per-row min1/min2 (no shuffles here)
      float cnv[4][4];
      int cbase = cc * 256 + wave * 64 + ((lane >> 4) << 2);
#pragma unroll
      for (int mf = 0; mf < 4; ++mf)
        *(float4*)cnv[mf] = *(const float4*)(cnorm + cbase + mf * 16);
#pragma unroll
      for (int nf = 0; nf < 4; ++nf) {
#pragma unroll
        for (int mf = 0; mf < 4; ++mf) {
#pragma unroll
          for (int r = 0; r < 4; ++r) {
            float s = cnv[mf][r] - 2.0f * acc[mf][nf][r];
            int c = cbase + mf * 16 + r;
            if (s < sv1[nf]) { sv2[nf] = sv1[nf]; sv1[nf] = s; si1[nf] = c; }
            else if (s < sv2[nf]) { sv2[nf] = s; }
          }
        }
        f32x4 z = {0.f, 0.f, 0.f, 0.f};
#pragma unroll
        for (int mf = 0; mf < 4; ++mf) acc[mf][nf] = z;
      }
    }
    __syncthreads();
  }

  // ---- final shuffle reduce across the 4 lane-groups (same rows, disjoint codes) ----
#pragma unroll
  for (int nf = 0; nf < 4; ++nf) {
#pragma unroll
    for (int off = 16; off < 64; off <<= 1) {
      float ov1 = __shfl_xor(sv1[nf], off);
      float ov2 = __shfl_xor(sv2[nf], off);
      int oi = __shfl_xor(si1[nf], off);
      if (ov1 < sv1[nf]) { sv2[nf] = fminf(sv1[nf], ov2); sv1[nf] = ov1; si1[nf] = oi; }
      else { sv2[nf] = fminf(sv2[nf], ov1); }
    }
  }

  // ---- cross-wave merge via LDS ----
  float* mv1 = (float*)As;          // 256 floats
  float* mv2 = mv1 + 256;
  int* mi1 = (int*)(mv2 + 256);
  if (lane < 16) {
#pragma unroll
    for (int nf = 0; nf < 4; ++nf) {
      int slot = ((wave * 4 + nf) << 4) + lane;
      mv1[slot] = sv1[nf]; mv2[slot] = sv2[nf]; mi1[slot] = si1[nf];
    }
  }
  __syncthreads();
  if (tid < 64) {
    float v1 = 3e38f, v2 = 3e38f;
    int i1 = 0;
    int rhi = tid >> 4, rlo = tid & 15;
#pragma unroll
    for (int w = 0; w < 4; ++w) {
      int slot = ((w * 4 + rhi) << 4) + rlo;
      float ov1 = mv1[slot], ov2 = mv2[slot];
      int oi = mi1[slot];
      if (ov1 < v1) { v2 = fminf(v1, ov2); v1 = ov1; i1 = oi; }
      else { v2 = fminf(v2, ov1); }
    }
    int grow = r0 + tid;
    out_idx[grow] = (float)i1;
    idxi[grow] = i1;
    if (v2 - v1 < MARGIN) {
      int p = atomicAdd(flagcount, 1);
      flagged[p] = grow;
    }
  }
}

// ---------------- exact fp32 re-ranking of flagged rows (parallel) ----------------
__global__ __launch_bounds__(256) void k_cleanup(const float* __restrict__ in,
                                                 const float* __restrict__ cb,
                                                 const float* __restrict__ cnorm,
                                                 const int* __restrict__ flagged,
                                                 const int* __restrict__ flagcount,
                                                 unsigned long long* __restrict__ packed) {
  __shared__ float xrow[EMBED_DIM];
  int tid = threadIdx.x;
  int nf = *flagcount;
  int chunk = blockIdx.x & 3;
  for (int fi = blockIdx.x >> 2; fi < nf; fi += 1024) {
    int row = flagged[fi];
    int batch = row >> 12, s = row & 4095;
    xrow[tid] = in[batch * (EMBED_DIM * SPATIAL) + tid * SPATIAL + s];
    __syncthreads();
    int code = chunk * 256 + tid;
    const float4* crow = (const float4*)(cb + code * EMBED_DIM);
    float dot = 0.f;
#pragma unroll
    for (int k4 = 0; k4 < 64; ++k4) {
      float4 c = crow[k4];
      dot += c.x * xrow[k4 * 4] + c.y * xrow[k4 * 4 + 1] + c.z * xrow[k4 * 4 + 2] +
             c.w * xrow[k4 * 4 + 3];
    }
    float sc = cnorm[code] - 2.0f * dot;
    unsigned long long p = ((unsigned long long)fkey(sc) << 32) | (unsigned)code;
    atomicMin(&packed[fi], p);
    __syncthreads();
  }
}

// ---------------- apply cleanup winners ----------------
__global__ __launch_bounds__(256) void k_fix(const int* __restrict__ flagged,
                                             const int* __restrict__ flagcount,
                                             const unsigned long long* __restrict__ packed,
                                             float* __restrict__ out_idx,
                                             int* __restrict__ idxi) {
  int nf = *flagcount;
  int i = blockIdx.x * 256 + threadIdx.x;
  if (i < nf) {
    int row = flagged[i];
    int idx = (int)(packed[i] & 0xffffffffull);
    out_idx[row] = (float)idx;
    idxi[row] = idx;
  }
}

// ---------------- mark used codes ----------------
__global__ __launch_bounds__(256) void k_used(const int* __restrict__ idxi,
                                              int* __restrict__ used) {
  int gid = blockIdx.x * 256 + threadIdx.x;
  used[idxi[gid]] = 1;
}

// ---------------- gather embed + MSE partial sums ----------------
__global__ __launch_bounds__(256) void k_gather(const float* __restrict__ in,
                                                const float* __restrict__ cb,
                                                const int* __restrict__ idxi,
                                                float* __restrict__ embed_out,
                                                double* __restrict__ partials) {
  int tid = threadIdx.x;
  float lsum = 0.f;
#pragma unroll
  for (int it = 0; it < 4; ++it) {
    int gid = (it * 4096 + blockIdx.x) * 256 + tid;
    int b = gid >> 18;
    int r = gid & 262143;
    int d = r >> 10;
    int s4 = r & 1023;
    int4 id4 = *(const int4*)(idxi + (b << 12) + (s4 << 2));
    int off = ((b * EMBED_DIM + d) << 12) + (s4 << 2);
    float4 x = *(const float4*)(in + off);
    float4 e;
    e.x = cb[id4.x * EMBED_DIM + d];
    e.y = cb[id4.y * EMBED_DIM + d];
    e.z = cb[id4.z * EMBED_DIM + d];
    e.w = cb[id4.w * EMBED_DIM + d];
    *(float4*)(embed_out + off) = e;
    float dx = e.x - x.x, dy = e.y - x.y, dz = e.z - x.z, dw = e.w - x.w;
    lsum += dx * dx + dy * dy + dz * dz + dw * dw;
  }
#pragma unroll
  for (int off = 1; off < 64; off <<= 1) lsum += __shfl_xor(lsum, off, 64);
  __shared__ float wsum[4];
  if ((tid & 63) == 0) wsum[tid >> 6] = lsum;
  __syncthreads();
  if (tid == 0)
    partials[blockIdx.x] = (double)(wsum[0] + wsum[1] + wsum[2] + wsum[3]);
}

// ---------------- tail: loss scalar + new_last_used ----------------
__global__ __launch_bounds__(256) void k_tail(const double* __restrict__ partials,
                                              const int* __restrict__ used,
                                              const int* __restrict__ last_used,
                                              float* __restrict__ out_loss,
                                              float* __restrict__ out_lu) {
  int tid = threadIdx.x;
  double s = 0.0;
  for (int i = tid; i < 4096; i += 256) s += partials[i];
#pragma unroll
  for (int off = 1; off < 64; off <<= 1) s += __shfl_xor(s, off, 64);
  __shared__ double sd[4];
  if ((tid & 63) == 0) sd[tid >> 6] = s;
  __syncthreads();
  if (tid == 0) {
    double total = sd[0] + sd[1] + sd[2] + sd[3];
    out_loss[0] = (float)(1.25 * total / (double)EMBED_ELEMS);
  }
  for (int i = tid; i < NUM_EMBED; i += 256)
    out_lu[i] = used[i] ? 0.0f : (float)(last_used[i] + 1);
}

extern "C" void kernel_launch(void* const* d_in, const int* in_sizes, int n_in,
                              void* d_out, int out_size, void* d_ws, size_t ws_size,
                              hipStream_t stream) {
  const float* in = (const float*)d_in[0];
  const float* cb = (const float*)d_in[1];
  const int* last_used = (const int*)d_in[2];

  float* out = (float*)d_out;
  float* out_idx = out;                        // 65536
  float* embed_out = out + NROWS;              // 16777216
  float* out_loss = embed_out + EMBED_ELEMS;   // 1
  float* out_lu = out_loss + 1;                // 1024

  unsigned long long* packed = (unsigned long long*)d_ws;  // 64K u64 (512 KB)
  _Float16* cb16 = (_Float16*)(packed + NROWS);            // 256K halves (512 KB, 16B-aligned)
  double* partials = (double*)(cb16 + NUM_EMBED * EMBED_DIM);  // 4096 double
  int* flagged = (int*)(partials + 4096);                  // 65536 int
  int* flagcount = flagged + NROWS;                        // 16 int (1 used)
  int* idxi = flagcount + 16;                              // 65536 int
  int* used = idxi + NROWS;                                // 1024 int
  float* cnorm = (float*)(used + NUM_EMBED);               // 1024 float

  hipLaunchKernelGGL(k_init, dim3(449), dim3(256), 0, stream, cb, packed, used, flagcount,
                     cnorm, cb16);
  hipLaunchKernelGGL(k_score, dim3(1024), dim3(256), 0, stream, in, cb16, cnorm, out_idx,
                     idxi, flagged, flagcount);
  hipLaunchKernelGGL(k_cleanup, dim3(4096), dim3(256), 0, stream, in, cb, cnorm, flagged,
                     flagcount, packed);
  hipLaunchKernelGGL(k_fix, dim3(256), dim3(256), 0, stream, flagged, flagcount, packed,
                     out_idx, idxi);
  hipLaunchKernelGGL(k_used, dim3(256), dim3(256), 0, stream, idxi, used);
  hipLaunchKernelGGL(k_gather, dim3(4096), dim3(256), 0, stream, in, cb, idxi, embed_out,
                     partials);
  hipLaunchKernelGGL(k_tail, dim3(1), dim3(256), 0, stream, partials, used, last_used,
                     out_loss, out_lu);
}

// Round 4
// 208.793 us; speedup vs baseline: 1.3787x; 1.3787x over previous
//
#include <hip/hip_runtime.h>

#define NUM_EMBED 1024
#define EMBED_DIM 256
#define SPATIAL 4096          // 64*64
#define NROWS 65536           // 16*4096
#define EMBED_ELEMS 16777216  // 16*256*4096
#define HMARGIN 0.05f         // margin on h = d2/2 scores (== 0.1 on d2)

typedef _Float16 half8 __attribute__((ext_vector_type(8)));
typedef float f32x4 __attribute__((ext_vector_type(4)));

__device__ __forceinline__ unsigned fkey(float f) {
  unsigned u = __float_as_uint(f);
  return (u & 0x80000000u) ? ~u : (u | 0x80000000u);
}

__device__ __forceinline__ void gll16(const _Float16* g, void* l) {
  __builtin_amdgcn_global_load_lds((const __attribute__((address_space(1))) void*)g,
                                   (__attribute__((address_space(3))) void*)l, 16, 0, 0);
}

// ---------------- init: used, flagcount, cnorm, cb16 ----------------
__global__ __launch_bounds__(256) void k_init(const float* __restrict__ cb,
                                              int* __restrict__ used,
                                              int* __restrict__ flagcount,
                                              float* __restrict__ cnorm,
                                              _Float16* __restrict__ cb16) {
  int bid = blockIdx.x, tid = threadIdx.x;
  if (bid == 0) {
    used[tid] = 0; used[tid + 256] = 0; used[tid + 512] = 0; used[tid + 768] = 0;
    if (tid == 0) *flagcount = 0;
  } else if (bid <= 64) {
    int c = (bid - 1) * 16 + (tid >> 4);
    int l = tid & 15;
    const float4* p = (const float4*)(cb + c * EMBED_DIM + l * 16);
    float s = 0.f;
#pragma unroll
    for (int j = 0; j < 4; ++j) {
      float4 v = p[j];
      s += v.x * v.x + v.y * v.y + v.z * v.z + v.w * v.w;
    }
#pragma unroll
    for (int off = 1; off < 16; off <<= 1) s += __shfl_xor(s, off, 16);
    if (l == 0) cnorm[c] = s;
  } else {
    int gid = (bid - 65) * 256 + tid;  // 0..32767
    const float4* src = (const float4*)(cb + gid * 8);
    float4 a = src[0], b = src[1];
    half8 h;
    h[0] = (_Float16)a.x; h[1] = (_Float16)a.y; h[2] = (_Float16)a.z; h[3] = (_Float16)a.w;
    h[4] = (_Float16)b.x; h[5] = (_Float16)b.y; h[6] = (_Float16)b.z; h[7] = (_Float16)b.w;
    *(half8*)(cb16 + gid * 8) = h;
  }
}

// ---------------- fp16 MFMA screening ----------------
// block: 64 rows x 1024 codes. 4 waves; wave = 64 codes x 64 rows per chunk.
// Xs [kc 0..31][row 0..63] 16B chunks (conflict-free). As[3] staging buffers
// [slot 0..3][code 0..255] 16B chunks, filled by global_load_lds (transpose via
// per-lane SOURCE address). K-loop: counted vmcnt(4) + raw s_barrier (T3+T4).
__global__ __launch_bounds__(256, 2) void k_score(const float* __restrict__ in,
                                                  const _Float16* __restrict__ cb16,
                                                  const float* __restrict__ cnorm,
                                                  float* __restrict__ out_idx,
                                                  int* __restrict__ idxi,
                                                  int* __restrict__ flagged,
                                                  int* __restrict__ flagcount) {
  __shared__ _Float16 Xs[16384];    // 32 KB
  __shared__ _Float16 As[3][8192];  // 3 x 16 KB
  int tid = threadIdx.x;
  int lane = tid & 63;
  int wave = tid >> 6;
  int ln = lane & 15;
  int lg = lane >> 4;
  int r0 = blockIdx.x << 6;
  const float* Ain = in + ((r0 >> 12) * (EMBED_DIM * SPATIAL)) + (r0 & 4095);

  // ---- stage X: fp32 -> fp16, [kc][row] 16B chunks (contiguous per 16 lanes) ----
  {
    int row = tid & 63;
    int kg8 = tid >> 6;  // 0..3
    const float* p0 = Ain + row;
#pragma unroll
    for (int j = 0; j < 8; ++j) {
      int kc = kg8 * 8 + j;  // 0..31
      int k0 = kc * 8;
      half8 h;
#pragma unroll
      for (int q = 0; q < 8; ++q) h[q] = (_Float16)p0[(k0 + q) * SPATIAL];
      *(half8*)((char*)Xs + kc * 1024 + row * 16) = h;
    }
  }

  // ---- cnorm*0.5 -> registers (64 scalars; static indexing after unroll) ----
  float cn[4][4][4];
#pragma unroll
  for (int cc = 0; cc < 4; ++cc)
#pragma unroll
    for (int mf = 0; mf < 4; ++mf) {
      float4 v = *(const float4*)(cnorm + cc * 256 + wave * 64 + mf * 16 + lg * 4);
      cn[cc][mf][0] = 0.5f * v.x; cn[cc][mf][1] = 0.5f * v.y;
      cn[cc][mf][2] = 0.5f * v.z; cn[cc][mf][3] = 0.5f * v.w;
    }

  const _Float16* ps0 = cb16 + tid * 256;  // code=tid row base

  __syncthreads();  // Xs visible (drains everything; prologue only)

  // prologue: issue stage(0) -> As[0], stage(1) -> As[1]
#pragma unroll
  for (int i = 0; i < 4; ++i) gll16(ps0 + i * 8, (char*)As[0] + i * 4096 + tid * 16);
#pragma unroll
  for (int i = 0; i < 4; ++i) gll16(ps0 + 32 + i * 8, (char*)As[1] + i * 4096 + tid * 16);

  f32x4 acc[4][4] = {};
  float sv1[4], sv2[4];
  int si1[4];
#pragma unroll
  for (int nf = 0; nf < 4; ++nf) { sv1[nf] = 3e38f; sv2[nf] = 3e38f; si1[nf] = 0; }

  int abase = lg * 4096 + (wave * 64 + ln) * 16;  // + mf*256
  int xbase = lg * 1024 + ln * 16;                // + ks*4096 + nf*256

#pragma unroll
  for (int cc = 0; cc < 4; ++cc) {
#pragma unroll
    for (int ks = 0; ks < 8; ++ks) {
      const int sc = cc * 8 + ks;
      // T4: counted wait — stage(sc) done, stage(sc+1) stays in flight
      if (sc < 31) { asm volatile("s_waitcnt vmcnt(4)" ::: "memory"); }
      else         { asm volatile("s_waitcnt vmcnt(0)" ::: "memory"); }
      __builtin_amdgcn_s_barrier();
      asm volatile("" ::: "memory");
      // issue stage(sc+2) -> As[(sc+2)%3] (buffer not in use at iters sc, sc+1)
      if (sc < 30) {
        const int ns = sc + 2;
        const int goff = ((ns >> 3) << 16) | ((ns & 7) << 5);  // halves
        char* dst = (char*)As[ns % 3];
#pragma unroll
        for (int i = 0; i < 4; ++i) gll16(ps0 + goff + i * 8, dst + i * 4096 + tid * 16);
      }
      // fragments + MFMA
      const char* Ac = (const char*)As[sc % 3];
      half8 af[4], bf[4];
#pragma unroll
      for (int mf = 0; mf < 4; ++mf) af[mf] = *(const half8*)(Ac + abase + mf * 256);
#pragma unroll
      for (int nf = 0; nf < 4; ++nf)
        bf[nf] = *(const half8*)((const char*)Xs + xbase + ks * 4096 + nf * 256);
      __builtin_amdgcn_s_setprio(1);
#pragma unroll
      for (int nf = 0; nf < 4; ++nf)
#pragma unroll
        for (int mf = 0; mf < 4; ++mf)
          acc[mf][nf] =
              __builtin_amdgcn_mfma_f32_16x16x32_f16(af[mf], bf[nf], acc[mf][nf], 0, 0, 0);
      __builtin_amdgcn_s_setprio(0);
      if (ks == 7) {
        // fold chunk cc: h = 0.5*cnorm - dot (argmin-equivalent to d2)
#pragma unroll
        for (int nf = 0; nf < 4; ++nf) {
#pragma unroll
          for (int mf = 0; mf < 4; ++mf) {
#pragma unroll
            for (int r = 0; r < 4; ++r) {
              float s = cn[cc][mf][r] - acc[mf][nf][r];
              int c = cc * 256 + wave * 64 + mf * 16 + lg * 4 + r;
              if (s < sv1[nf]) { sv2[nf] = sv1[nf]; sv1[nf] = s; si1[nf] = c; }
              else if (s < sv2[nf]) { sv2[nf] = s; }
            }
          }
          f32x4 z = {0.f, 0.f, 0.f, 0.f};
#pragma unroll
          for (int mf = 0; mf < 4; ++mf) acc[mf][nf] = z;
        }
      }
    }
  }

  // ---- merge lane-groups (same rows, disjoint codes) ----
#pragma unroll
  for (int nf = 0; nf < 4; ++nf) {
#pragma unroll
    for (int off = 16; off < 64; off <<= 1) {
      float ov1 = __shfl_xor(sv1[nf], off);
      float ov2 = __shfl_xor(sv2[nf], off);
      int oi = __shfl_xor(si1[nf], off);
      if (ov1 < sv1[nf]) { sv2[nf] = fminf(sv1[nf], ov2); sv1[nf] = ov1; si1[nf] = oi; }
      else { sv2[nf] = fminf(sv2[nf], ov1); }
    }
  }

  // ---- cross-wave merge via LDS (reuse As) ----
  __syncthreads();
  float* mv1 = (float*)As;  // 256 f
  float* mv2 = mv1 + 256;
  int* mi1 = (int*)(mv2 + 256);
  if (lane < 16) {
#pragma unroll
    for (int nf = 0; nf < 4; ++nf) {
      int slot = ((wave * 4 + nf) << 4) + lane;
      mv1[slot] = sv1[nf]; mv2[slot] = sv2[nf]; mi1[slot] = si1[nf];
    }
  }
  __syncthreads();
  if (tid < 64) {
    float v1 = 3e38f, v2 = 3e38f;
    int i1 = 0;
    int rhi = tid >> 4, rlo = tid & 15;
#pragma unroll
    for (int w = 0; w < 4; ++w) {
      int slot = ((w * 4 + rhi) << 4) + rlo;
      float ov1 = mv1[slot], ov2 = mv2[slot];
      int oi = mi1[slot];
      if (ov1 < v1) { v2 = fminf(v1, ov2); v1 = ov1; i1 = oi; }
      else { v2 = fminf(v2, ov1); }
    }
    int grow = r0 + tid;
    out_idx[grow] = (float)i1;
    idxi[grow] = i1;
    if (v2 - v1 < HMARGIN) {
      int p = atomicAdd(flagcount, 1);
      flagged[p] = grow;
    }
  }
}

// ---------------- exact fp32 re-rank: 8 flagged rows per block, block-local ----------------
__global__ __launch_bounds__(256) void k_cleanup(const float* __restrict__ in,
                                                 const float* __restrict__ cb,
                                                 const float* __restrict__ cnorm,
                                                 const int* __restrict__ flagged,
                                                 const int* __restrict__ flagcount,
                                                 float* __restrict__ out_idx,
                                                 int* __restrict__ idxi) {
  __shared__ float xs[8][256];
  __shared__ unsigned long long red[4][8];
  int tid = threadIdx.x;
  int lane = tid & 63;
  int wave = tid >> 6;
  int nf = *flagcount;
  const float4* cb4 = (const float4*)cb;
  for (int g = blockIdx.x; g * 8 < nf; g += 1024) {
    int base = g * 8;
    int cnt = nf - base; if (cnt > 8) cnt = 8;
    {  // stage 8 rows (clamped)
      int j = tid >> 5;
      int k0 = (tid & 31) * 8;
      int fi = base + j;
      int row = flagged[fi < nf ? fi : base];
      int b = row >> 12, s = row & 4095;
      const float* p = in + b * (EMBED_DIM * SPATIAL) + s;
#pragma unroll
      for (int q = 0; q < 8; ++q) xs[j][k0 + q] = p[(k0 + q) * SPATIAL];
    }
    __syncthreads();
    float acc[4][8] = {};  // [code_i][row]
    for (int k4 = 0; k4 < 64; ++k4) {
      float4 cw[4];
#pragma unroll
      for (int i = 0; i < 4; ++i) cw[i] = cb4[(tid + 256 * i) * 64 + k4];
#pragma unroll
      for (int r = 0; r < 8; ++r) {
        float4 xv = *(const float4*)&xs[r][k4 * 4];
#pragma unroll
        for (int i = 0; i < 4; ++i)
          acc[i][r] += cw[i].x * xv.x + cw[i].y * xv.y + cw[i].z * xv.z + cw[i].w * xv.w;
      }
    }
    float cnl[4];
#pragma unroll
    for (int i = 0; i < 4; ++i) cnl[i] = cnorm[tid + 256 * i];
#pragma unroll
    for (int r = 0; r < 8; ++r) {
      unsigned long long b = ~0ull;
#pragma unroll
      for (int i = 0; i < 4; ++i) {
        float s = cnl[i] - 2.0f * acc[i][r];
        unsigned long long p =
            ((unsigned long long)fkey(s) << 32) | (unsigned)(tid + 256 * i);
        b = p < b ? p : b;
      }
#pragma unroll
      for (int off = 1; off < 64; off <<= 1) {
        unsigned long long o = __shfl_xor(b, off);
        b = o < b ? o : b;
      }
      if (lane == 0) red[wave][r] = b;
    }
    __syncthreads();
    if (tid < cnt) {
      unsigned long long b = red[0][tid];
#pragma unroll
      for (int w = 1; w < 4; ++w) { unsigned long long o = red[w][tid]; b = o < b ? o : b; }
      int row = flagged[base + tid];
      int idx = (int)(b & 0xffffffffull);
      out_idx[row] = (float)idx;
      idxi[row] = idx;
    }
    __syncthreads();
  }
}

// ---------------- mark used codes ----------------
__global__ __launch_bounds__(256) void k_used(const int* __restrict__ idxi,
                                              int* __restrict__ used) {
  int gid = blockIdx.x * 256 + threadIdx.x;
  used[idxi[gid]] = 1;
}

// ---------------- gather embed + MSE partial sums ----------------
__global__ __launch_bounds__(256) void k_gather(const float* __restrict__ in,
                                                const float* __restrict__ cb,
                                                const int* __restrict__ idxi,
                                                float* __restrict__ embed_out,
                                                double* __restrict__ partials) {
  int tid = threadIdx.x;
  float lsum = 0.f;
#pragma unroll
  for (int it = 0; it < 4; ++it) {
    int gid = (it * 4096 + blockIdx.x) * 256 + tid;
    int b = gid >> 18;
    int r = gid & 262143;
    int d = r >> 10;
    int s4 = r & 1023;
    int4 id4 = *(const int4*)(idxi + (b << 12) + (s4 << 2));
    int off = ((b * EMBED_DIM + d) << 12) + (s4 << 2);
    float4 x = *(const float4*)(in + off);
    float4 e;
    e.x = cb[id4.x * EMBED_DIM + d];
    e.y = cb[id4.y * EMBED_DIM + d];
    e.z = cb[id4.z * EMBED_DIM + d];
    e.w = cb[id4.w * EMBED_DIM + d];
    *(float4*)(embed_out + off) = e;
    float dx = e.x - x.x, dy = e.y - x.y, dz = e.z - x.z, dw = e.w - x.w;
    lsum += dx * dx + dy * dy + dz * dz + dw * dw;
  }
#pragma unroll
  for (int off = 1; off < 64; off <<= 1) lsum += __shfl_xor(lsum, off, 64);
  __shared__ float wsum[4];
  if ((tid & 63) == 0) wsum[tid >> 6] = lsum;
  __syncthreads();
  if (tid == 0)
    partials[blockIdx.x] = (double)(wsum[0] + wsum[1] + wsum[2] + wsum[3]);
}

// ---------------- tail: loss scalar + new_last_used ----------------
__global__ __launch_bounds__(256) void k_tail(const double* __restrict__ partials,
                                              const int* __restrict__ used,
                                              const int* __restrict__ last_used,
                                              float* __restrict__ out_loss,
                                              float* __restrict__ out_lu) {
  int tid = threadIdx.x;
  double s = 0.0;
  for (int i = tid; i < 4096; i += 256) s += partials[i];
#pragma unroll
  for (int off = 1; off < 64; off <<= 1) s += __shfl_xor(s, off, 64);
  __shared__ double sd[4];
  if ((tid & 63) == 0) sd[tid >> 6] = s;
  __syncthreads();
  if (tid == 0) {
    double total = sd[0] + sd[1] + sd[2] + sd[3];
    out_loss[0] = (float)(1.25 * total / (double)EMBED_ELEMS);
  }
  for (int i = tid; i < NUM_EMBED; i += 256)
    out_lu[i] = used[i] ? 0.0f : (float)(last_used[i] + 1);
}

extern "C" void kernel_launch(void* const* d_in, const int* in_sizes, int n_in,
                              void* d_out, int out_size, void* d_ws, size_t ws_size,
                              hipStream_t stream) {
  const float* in = (const float*)d_in[0];
  const float* cb = (const float*)d_in[1];
  const int* last_used = (const int*)d_in[2];

  float* out = (float*)d_out;
  float* out_idx = out;                       // 65536
  float* embed_out = out + NROWS;             // 16777216
  float* out_loss = embed_out + EMBED_ELEMS;  // 1
  float* out_lu = out_loss + 1;               // 1024

  _Float16* cb16 = (_Float16*)d_ws;                            // 256K halves (512 KB)
  double* partials = (double*)(cb16 + NUM_EMBED * EMBED_DIM);  // 4096 double
  int* flagged = (int*)(partials + 4096);                      // 65536 int
  int* flagcount = flagged + NROWS;                            // 16 int
  int* idxi = flagcount + 16;                                  // 65536 int
  int* used = idxi + NROWS;                                    // 1024 int
  float* cnorm = (float*)(used + NUM_EMBED);                   // 1024 float

  hipLaunchKernelGGL(k_init, dim3(193), dim3(256), 0, stream, cb, used, flagcount, cnorm, cb16);
  hipLaunchKernelGGL(k_score, dim3(1024), dim3(256), 0, stream, in, cb16, cnorm, out_idx,
                     idxi, flagged, flagcount);
  hipLaunchKernelGGL(k_cleanup, dim3(1024), dim3(256), 0, stream, in, cb, cnorm, flagged,
                     flagcount, out_idx, idxi);
  hipLaunchKernelGGL(k_used, dim3(256), dim3(256), 0, stream, idxi, used);
  hipLaunchKernelGGL(k_gather, dim3(4096), dim3(256), 0, stream, in, cb, idxi, embed_out,
                     partials);
  hipLaunchKernelGGL(k_tail, dim3(1), dim3(256), 0, stream, partials, used, last_used,
                     out_loss, out_lu);
}

// Round 5
// 183.514 us; speedup vs baseline: 1.5686x; 1.1377x over previous
//
#include <hip/hip_runtime.h>

#define NUM_EMBED 1024
#define EMBED_DIM 256
#define SPATIAL 4096          // 64*64
#define NROWS 65536           // 16*4096
#define EMBED_ELEMS 16777216  // 16*256*4096
#define HMARGIN 0.05f         // margin on h = d2/2 scores (== 0.1 on d2)

typedef _Float16 half8 __attribute__((ext_vector_type(8)));
typedef float f32x4 __attribute__((ext_vector_type(4)));

__device__ __forceinline__ unsigned fkey(float f) {
  unsigned u = __float_as_uint(f);
  return (u & 0x80000000u) ? ~u : (u | 0x80000000u);
}

__device__ __forceinline__ void gll16(const _Float16* g, void* l) {
  __builtin_amdgcn_global_load_lds((const __attribute__((address_space(1))) void*)g,
                                   (__attribute__((address_space(3))) void*)l, 16, 0, 0);
}

// ---------------- init: used, flagcount, cnorm, cb16 ----------------
__global__ __launch_bounds__(256) void k_init(const float* __restrict__ cb,
                                              int* __restrict__ used,
                                              int* __restrict__ flagcount,
                                              float* __restrict__ cnorm,
                                              _Float16* __restrict__ cb16) {
  int bid = blockIdx.x, tid = threadIdx.x;
  if (bid == 0) {
    used[tid] = 0; used[tid + 256] = 0; used[tid + 512] = 0; used[tid + 768] = 0;
    if (tid == 0) *flagcount = 0;
  } else if (bid <= 64) {
    int c = (bid - 1) * 16 + (tid >> 4);
    int l = tid & 15;
    const float4* p = (const float4*)(cb + c * EMBED_DIM + l * 16);
    float s = 0.f;
#pragma unroll
    for (int j = 0; j < 4; ++j) {
      float4 v = p[j];
      s += v.x * v.x + v.y * v.y + v.z * v.z + v.w * v.w;
    }
#pragma unroll
    for (int off = 1; off < 16; off <<= 1) s += __shfl_xor(s, off, 16);
    if (l == 0) cnorm[c] = s;
  } else {
    int gid = (bid - 65) * 256 + tid;  // 0..32767
    const float4* src = (const float4*)(cb + gid * 8);
    float4 a = src[0], b = src[1];
    half8 h;
    h[0] = (_Float16)a.x; h[1] = (_Float16)a.y; h[2] = (_Float16)a.z; h[3] = (_Float16)a.w;
    h[4] = (_Float16)b.x; h[5] = (_Float16)b.y; h[6] = (_Float16)b.z; h[7] = (_Float16)b.w;
    *(half8*)(cb16 + gid * 8) = h;
  }
}

// ---------------- fp16 MFMA screening, X-in-registers ----------------
// block: 128 rows (4 waves x 32 rows), all 1024 codes in 32 chunks of 32.
// X frags: 64 VGPRs/lane (one-time LDS transpose). Per chunk: 1 barrier,
// 16 ds_read_b128 (A-frags) + 32 MFMA, counted vmcnt(4), 3-deep LDS ring.
__global__ __launch_bounds__(256, 2) void k_score(const float* __restrict__ in,
                                                  const _Float16* __restrict__ cb16,
                                                  const float* __restrict__ cnorm,
                                                  float* __restrict__ out_idx,
                                                  int* __restrict__ idxi,
                                                  int* __restrict__ flagged,
                                                  int* __restrict__ flagcount) {
  __shared__ _Float16 As[3][8192];  // 3 x 16 KB ring
  __shared__ float cn_lds[1024];    // 4 KB, pre-scaled x0.5
  int tid = threadIdx.x;
  int lane = tid & 63;
  int wave = tid >> 6;
  int ln = lane & 15;
  int lg = lane >> 4;
  int r0 = blockIdx.x << 7;  // 128 rows/block
  int batch = r0 >> 12, s0 = r0 & 4095;
  const float* Ain = in + batch * (EMBED_DIM * SPATIAL) + s0;

  // cnorm*0.5 -> LDS
#pragma unroll
  for (int i = 0; i < 4; ++i) cn_lds[tid + 256 * i] = 0.5f * cnorm[tid + 256 * i];

  // ---- one-time X transpose: wave w stages its 32 rows into a 16KB buffer,
  //      then loads its 16 B-fragments (xf) to registers. Slice layout:
  //      [kc 0..31][row 0..31] 16B entries at byte kc*512 + row*16.
  half8 xf[8][2];
  {
    int row = lane & 31;
    int khalf = lane >> 5;  // 0/1 -> kc 0..15 / 16..31
    const float* p0 = Ain + wave * 32 + row;
    if (wave < 3) {
      char* base = (char*)As[wave];
#pragma unroll
      for (int j = 0; j < 16; ++j) {
        int kc = khalf * 16 + j;
        half8 h;
#pragma unroll
        for (int q = 0; q < 8; ++q) h[q] = (_Float16)p0[(kc * 8 + q) * SPATIAL];
        *(half8*)(base + kc * 512 + row * 16) = h;
      }
    }
    __syncthreads();
    if (wave < 3) {
      const char* base = (const char*)As[wave];
#pragma unroll
      for (int ks = 0; ks < 8; ++ks)
#pragma unroll
        for (int nf = 0; nf < 2; ++nf)
          xf[ks][nf] = *(const half8*)(base + (ks * 4 + lg) * 512 + (nf * 16 + ln) * 16);
    }
    __syncthreads();  // waves 0..2 done reading before wave 3 reuses As[0]
    if (wave == 3) {
      char* base = (char*)As[0];
#pragma unroll
      for (int j = 0; j < 16; ++j) {
        int kc = khalf * 16 + j;
        half8 h;
#pragma unroll
        for (int q = 0; q < 8; ++q) h[q] = (_Float16)p0[(kc * 8 + q) * SPATIAL];
        *(half8*)(base + kc * 512 + row * 16) = h;
      }
      const char* cbase = (const char*)As[0];
#pragma unroll
      for (int ks = 0; ks < 8; ++ks)
#pragma unroll
        for (int nf = 0; nf < 2; ++nf)
          xf[ks][nf] = *(const half8*)(cbase + (ks * 4 + lg) * 512 + (nf * 16 + ln) * 16);
    }
    __syncthreads();  // As free for codebook ring
  }

  // per-thread gll16 source base: code (t&31), k-slot (t>>5)
  const _Float16* pc = cb16 + (tid & 31) * 256 + (tid >> 5) * 8;

  // prologue: chunks 0,1 -> As[0],As[1]
#pragma unroll
  for (int i = 0; i < 4; ++i) gll16(pc + i * 64, (char*)As[0] + i * 4096 + tid * 16);
#pragma unroll
  for (int i = 0; i < 4; ++i) gll16(pc + 8192 + i * 64, (char*)As[1] + i * 4096 + tid * 16);

  float sv1[2] = {3e38f, 3e38f}, sv2[2] = {3e38f, 3e38f};
  int si1[2] = {0, 0};

#pragma unroll
  for (int c = 0; c < 32; ++c) {
    // counted wait: chunk c's 4 loads done, chunk c+1's stay in flight
    if (c < 31) { asm volatile("s_waitcnt vmcnt(4)" ::: "memory"); }
    else        { asm volatile("s_waitcnt vmcnt(0)" ::: "memory"); }
    __builtin_amdgcn_s_barrier();
    asm volatile("" ::: "memory");
    if (c < 30) {
      char* dst = (char*)As[(c + 2) % 3];
#pragma unroll
      for (int i = 0; i < 4; ++i)
        gll16(pc + (c + 2) * 8192 + i * 64, dst + i * 4096 + tid * 16);
    }
    const char* Ac = (const char*)As[c % 3];
    f32x4 acc[2][2] = {};
    __builtin_amdgcn_s_setprio(1);
#pragma unroll
    for (int ks = 0; ks < 8; ++ks) {
      half8 af0 = *(const half8*)(Ac + (ks * 4 + lg) * 512 + ln * 16);
      half8 af1 = *(const half8*)(Ac + (ks * 4 + lg) * 512 + 256 + ln * 16);
      acc[0][0] = __builtin_amdgcn_mfma_f32_16x16x32_f16(af0, xf[ks][0], acc[0][0], 0, 0, 0);
      acc[0][1] = __builtin_amdgcn_mfma_f32_16x16x32_f16(af0, xf[ks][1], acc[0][1], 0, 0, 0);
      acc[1][0] = __builtin_amdgcn_mfma_f32_16x16x32_f16(af1, xf[ks][0], acc[1][0], 0, 0, 0);
      acc[1][1] = __builtin_amdgcn_mfma_f32_16x16x32_f16(af1, xf[ks][1], acc[1][1], 0, 0, 0);
    }
    __builtin_amdgcn_s_setprio(0);
    // fold chunk: h = 0.5*|c|^2 - x.c  (argmin-equivalent to d2)
#pragma unroll
    for (int mf = 0; mf < 2; ++mf) {
      float cna[4];
      *(float4*)cna = *(const float4*)(cn_lds + c * 32 + mf * 16 + lg * 4);
#pragma unroll
      for (int nf = 0; nf < 2; ++nf) {
#pragma unroll
        for (int r = 0; r < 4; ++r) {
          float s = cna[r] - acc[mf][nf][r];
          int code = c * 32 + mf * 16 + lg * 4 + r;
          if (s < sv1[nf]) { sv2[nf] = sv1[nf]; sv1[nf] = s; si1[nf] = code; }
          else if (s < sv2[nf]) { sv2[nf] = s; }
        }
      }
    }
  }

  // ---- merge the 4 lane-groups (same rows, disjoint codes); no cross-wave ----
#pragma unroll
  for (int nf = 0; nf < 2; ++nf) {
#pragma unroll
    for (int off = 16; off < 64; off <<= 1) {
      float ov1 = __shfl_xor(sv1[nf], off);
      float ov2 = __shfl_xor(sv2[nf], off);
      int oi = __shfl_xor(si1[nf], off);
      if (ov1 < sv1[nf]) { sv2[nf] = fminf(sv1[nf], ov2); sv1[nf] = ov1; si1[nf] = oi; }
      else { sv2[nf] = fminf(sv2[nf], ov1); }
    }
  }
  if (lg == 0) {
#pragma unroll
    for (int nf = 0; nf < 2; ++nf) {
      int grow = r0 + wave * 32 + nf * 16 + ln;
      out_idx[grow] = (float)si1[nf];
      idxi[grow] = si1[nf];
      if (sv2[nf] - sv1[nf] < HMARGIN) {
        int p = atomicAdd(flagcount, 1);
        flagged[p] = grow;
      }
    }
  }
}

// ---------------- exact fp32 re-rank: 8 flagged rows per block ----------------
__global__ __launch_bounds__(256) void k_cleanup(const float* __restrict__ in,
                                                 const float* __restrict__ cb,
                                                 const float* __restrict__ cnorm,
                                                 const int* __restrict__ flagged,
                                                 const int* __restrict__ flagcount,
                                                 float* __restrict__ out_idx,
                                                 int* __restrict__ idxi) {
  __shared__ float xs[8][256];
  __shared__ unsigned long long red[4][8];
  int tid = threadIdx.x;
  int lane = tid & 63;
  int wave = tid >> 6;
  int nf = *flagcount;
  const float4* cb4 = (const float4*)cb;
  for (int g = blockIdx.x; g * 8 < nf; g += 1024) {
    int base = g * 8;
    int cnt = nf - base; if (cnt > 8) cnt = 8;
    {
      int j = tid >> 5;
      int k0 = (tid & 31) * 8;
      int fi = base + j;
      int row = flagged[fi < nf ? fi : base];
      int b = row >> 12, s = row & 4095;
      const float* p = in + b * (EMBED_DIM * SPATIAL) + s;
#pragma unroll
      for (int q = 0; q < 8; ++q) xs[j][k0 + q] = p[(k0 + q) * SPATIAL];
    }
    __syncthreads();
    float acc[4][8] = {};
    for (int k4 = 0; k4 < 64; ++k4) {
      float4 cw[4];
#pragma unroll
      for (int i = 0; i < 4; ++i) cw[i] = cb4[(tid + 256 * i) * 64 + k4];
#pragma unroll
      for (int r = 0; r < 8; ++r) {
        float4 xv = *(const float4*)&xs[r][k4 * 4];
#pragma unroll
        for (int i = 0; i < 4; ++i)
          acc[i][r] += cw[i].x * xv.x + cw[i].y * xv.y + cw[i].z * xv.z + cw[i].w * xv.w;
      }
    }
    float cnl[4];
#pragma unroll
    for (int i = 0; i < 4; ++i) cnl[i] = cnorm[tid + 256 * i];
#pragma unroll
    for (int r = 0; r < 8; ++r) {
      unsigned long long b = ~0ull;
#pragma unroll
      for (int i = 0; i < 4; ++i) {
        float s = cnl[i] - 2.0f * acc[i][r];
        unsigned long long p =
            ((unsigned long long)fkey(s) << 32) | (unsigned)(tid + 256 * i);
        b = p < b ? p : b;
      }
#pragma unroll
      for (int off = 1; off < 64; off <<= 1) {
        unsigned long long o = __shfl_xor(b, off);
        b = o < b ? o : b;
      }
      if (lane == 0) red[wave][r] = b;
    }
    __syncthreads();
    if (tid < cnt) {
      unsigned long long b = red[0][tid];
#pragma unroll
      for (int w = 1; w < 4; ++w) { unsigned long long o = red[w][tid]; b = o < b ? o : b; }
      int row = flagged[base + tid];
      int idx = (int)(b & 0xffffffffull);
      out_idx[row] = (float)idx;
      idxi[row] = idx;
    }
    __syncthreads();
  }
}

// ---------------- mark used codes ----------------
__global__ __launch_bounds__(256) void k_used(const int* __restrict__ idxi,
                                              int* __restrict__ used) {
  int gid = blockIdx.x * 256 + threadIdx.x;
  used[idxi[gid]] = 1;
}

// ---------------- gather embed + MSE partial sums ----------------
__global__ __launch_bounds__(256) void k_gather(const float* __restrict__ in,
                                                const float* __restrict__ cb,
                                                const int* __restrict__ idxi,
                                                float* __restrict__ embed_out,
                                                double* __restrict__ partials) {
  int tid = threadIdx.x;
  float lsum = 0.f;
#pragma unroll
  for (int it = 0; it < 4; ++it) {
    int gid = (it * 4096 + blockIdx.x) * 256 + tid;
    int b = gid >> 18;
    int r = gid & 262143;
    int d = r >> 10;
    int s4 = r & 1023;
    int4 id4 = *(const int4*)(idxi + (b << 12) + (s4 << 2));
    int off = ((b * EMBED_DIM + d) << 12) + (s4 << 2);
    float4 x = *(const float4*)(in + off);
    float4 e;
    e.x = cb[id4.x * EMBED_DIM + d];
    e.y = cb[id4.y * EMBED_DIM + d];
    e.z = cb[id4.z * EMBED_DIM + d];
    e.w = cb[id4.w * EMBED_DIM + d];
    *(float4*)(embed_out + off) = e;
    float dx = e.x - x.x, dy = e.y - x.y, dz = e.z - x.z, dw = e.w - x.w;
    lsum += dx * dx + dy * dy + dz * dz + dw * dw;
  }
#pragma unroll
  for (int off = 1; off < 64; off <<= 1) lsum += __shfl_xor(lsum, off, 64);
  __shared__ float wsum[4];
  if ((tid & 63) == 0) wsum[tid >> 6] = lsum;
  __syncthreads();
  if (tid == 0)
    partials[blockIdx.x] = (double)(wsum[0] + wsum[1] + wsum[2] + wsum[3]);
}

// ---------------- tail: loss scalar + new_last_used ----------------
__global__ __launch_bounds__(256) void k_tail(const double* __restrict__ partials,
                                              const int* __restrict__ used,
                                              const int* __restrict__ last_used,
                                              float* __restrict__ out_loss,
                                              float* __restrict__ out_lu) {
  int tid = threadIdx.x;
  double s = 0.0;
  for (int i = tid; i < 4096; i += 256) s += partials[i];
#pragma unroll
  for (int off = 1; off < 64; off <<= 1) s += __shfl_xor(s, off, 64);
  __shared__ double sd[4];
  if ((tid & 63) == 0) sd[tid >> 6] = s;
  __syncthreads();
  if (tid == 0) {
    double total = sd[0] + sd[1] + sd[2] + sd[3];
    out_loss[0] = (float)(1.25 * total / (double)EMBED_ELEMS);
  }
  for (int i = tid; i < NUM_EMBED; i += 256)
    out_lu[i] = used[i] ? 0.0f : (float)(last_used[i] + 1);
}

extern "C" void kernel_launch(void* const* d_in, const int* in_sizes, int n_in,
                              void* d_out, int out_size, void* d_ws, size_t ws_size,
                              hipStream_t stream) {
  const float* in = (const float*)d_in[0];
  const float* cb = (const float*)d_in[1];
  const int* last_used = (const int*)d_in[2];

  float* out = (float*)d_out;
  float* out_idx = out;                       // 65536
  float* embed_out = out + NROWS;             // 16777216
  float* out_loss = embed_out + EMBED_ELEMS;  // 1
  float* out_lu = out_loss + 1;               // 1024

  _Float16* cb16 = (_Float16*)d_ws;                            // 512 KB
  double* partials = (double*)(cb16 + NUM_EMBED * EMBED_DIM);  // 4096 double
  int* flagged = (int*)(partials + 4096);                      // 65536 int
  int* flagcount = flagged + NROWS;                            // 16 int
  int* idxi = flagcount + 16;                                  // 65536 int
  int* used = idxi + NROWS;                                    // 1024 int
  float* cnorm = (float*)(used + NUM_EMBED);                   // 1024 float

  hipLaunchKernelGGL(k_init, dim3(193), dim3(256), 0, stream, cb, used, flagcount, cnorm, cb16);
  hipLaunchKernelGGL(k_score, dim3(512), dim3(256), 0, stream, in, cb16, cnorm, out_idx,
                     idxi, flagged, flagcount);
  hipLaunchKernelGGL(k_cleanup, dim3(1024), dim3(256), 0, stream, in, cb, cnorm, flagged,
                     flagcount, out_idx, idxi);
  hipLaunchKernelGGL(k_used, dim3(256), dim3(256), 0, stream, idxi, used);
  hipLaunchKernelGGL(k_gather, dim3(4096), dim3(256), 0, stream, in, cb, idxi, embed_out,
                     partials);
  hipLaunchKernelGGL(k_tail, dim3(1), dim3(256), 0, stream, partials, used, last_used,
                     out_loss, out_lu);
}